// Round 1
// 199.458 us; speedup vs baseline: 1.0146x; 1.0146x over previous
//
#include <hip/hip_runtime.h>
#include <stdint.h>
#include <stddef.h>

// Reference collapse:
//   softmax over k sums to 1 and the einsum applies it pointwise to v,
//   so out = conv1x1(conv1x1(x, W_v, b_v), W_proj, b_proj)
//          = (W_proj @ W_v) @ x  + (W_proj @ b_v + b_proj)
// One 192x192 bf16-MFMA GEMM over 8*16384 pixels. Memory-bound (~201 MB).
//
// v2: latency-bound fix (all pipes were idle: MfmaUtil 5%, VALU 6%, HBM 27%).
//   - 4 tiles per block, double-buffered LDS, register-prefetch of tile t+1
//     issued before compute of tile t (async-split staging).
//   - A fragments + bias hoisted out of the tile loop (72+12 VGPRs) so the
//     vmcnt queue only carries the x prefetch + output stores.
//   - B fragments read once per tile (pt-outer loop): 24 ds_read_b128
//     instead of 72.

#define CDIM 192
#define HWPX 16384
#define LDS_STRIDE 200  // 192 + 8 pad (ushorts)
#define T_TILES 4       // tiles per block; grid = 2048/4 = 512 = 2 blocks/CU

typedef __attribute__((ext_vector_type(8))) short short8;
typedef __attribute__((ext_vector_type(4))) float floatx4;
typedef __attribute__((ext_vector_type(4))) unsigned short ushort4_t;

__device__ __forceinline__ unsigned short f2bf(float f) {
    union { float f; unsigned int u; } v; v.f = f;
    unsigned int r = (v.u + 0x7FFFu + ((v.u >> 16) & 1u)) >> 16;  // RTNE
    return (unsigned short)r;
}

// ---- prep: M = W_proj @ W_v (bf16), bias = W_proj @ b_v + b_proj ----
__global__ __launch_bounds__(192) void prep_kernel(
    const float* __restrict__ w_qkv, const float* __restrict__ b_qkv,
    const float* __restrict__ w_proj, const float* __restrict__ b_proj,
    unsigned short* __restrict__ Mb, float* __restrict__ bias)
{
    const int o = blockIdx.x, c = threadIdx.x;
    const float* wpr = w_proj + o * CDIM;
    const float* wv  = w_qkv + 2 * CDIM * CDIM;  // v-rows of w_qkv
    float acc = 0.f;
    #pragma unroll 32
    for (int k = 0; k < CDIM; ++k)
        acc = fmaf(wpr[k], wv[k * CDIM + c], acc);
    Mb[o * CDIM + c] = f2bf(acc);

    __shared__ float red[CDIM];
    red[c] = wpr[c] * b_qkv[2 * CDIM + c];
    __syncthreads();
    if (c < 64) {
        float v = red[c] + red[c + 64] + red[c + 128];
        #pragma unroll
        for (int off = 32; off > 0; off >>= 1) v += __shfl_down(v, off);
        if (c == 0) bias[o] = v + b_proj[o];
    }
}

// ---- main: out[b, :, p0:p0+64] = M @ x[b, :, p0:p0+64] + bias ----
__global__ __launch_bounds__(256, 2) void fused_kernel(
    const float* __restrict__ x,
    const unsigned short* __restrict__ Mb,
    const float* __restrict__ bias,
    float* __restrict__ out)
{
    __shared__ unsigned short Xl[2][64 * LDS_STRIDE];  // 2 x 25.6 KB double buffer

    const int tid  = threadIdx.x;
    const int lane = tid & 63;
    const int w    = tid >> 6;    // wave 0..3
    const int n    = lane & 15;   // MFMA n / m-lane index
    const int q    = lane >> 4;   // MFMA quad

    // staging geometry: slot = it*256 + tid  ->  p4 = tid&15 (const),
    // cg4 = it*16 + (tid>>4)
    const int p4  = tid & 15;     // pixel group (4 px)
    const int cg0 = tid >> 4;     // channel-group base (0..15)

    const int tile0 = blockIdx.x * T_TILES;

    // issue the 12 float4 loads of one tile into registers (no wait here)
    auto load_tile = [&](int tile, floatx4* fl) {
        const float* xb = x + (size_t)(tile >> 8) * (CDIM * HWPX)
                            + ((tile & 255) << 6);
        const float* src0 = xb + (size_t)(cg0 * 4) * HWPX + p4 * 4;
        #pragma unroll
        for (int it = 0; it < 3; ++it) {
            const float* src = src0 + (size_t)(it * 64) * HWPX;
            #pragma unroll
            for (int j = 0; j < 4; ++j)
                fl[it * 4 + j] = *(const floatx4*)(src + (size_t)j * HWPX);
        }
    };

    // convert fp32 -> bf16 and write transposed [p][c] into LDS buffer
    auto stage_tile = [&](int buf, const floatx4* fl) {
        #pragma unroll
        for (int it = 0; it < 3; ++it) {
            unsigned short* dst =
                &Xl[buf][p4 * 4 * LDS_STRIDE + (it * 16 + cg0) * 4];
            #pragma unroll
            for (int i = 0; i < 4; ++i) {
                ushort4_t v4;
                v4.x = f2bf(fl[it * 4 + 0][i]);
                v4.y = f2bf(fl[it * 4 + 1][i]);
                v4.z = f2bf(fl[it * 4 + 2][i]);
                v4.w = f2bf(fl[it * 4 + 3][i]);
                *(ushort4_t*)(dst + i * LDS_STRIDE) = v4;
            }
        }
    };

    // hoisted A fragments (wave w covers output channels [w*48, w*48+48))
    // and bias values — loaded once, reused for all T_TILES tiles.
    short8 a[3][6];
    float  bo[3][4];
    #pragma unroll
    for (int t = 0; t < 3; ++t) {
        const int ot = w * 3 + t;
        const unsigned short* arow = Mb + (ot * 16 + n) * CDIM + q * 8;
        #pragma unroll
        for (int ks = 0; ks < 6; ++ks)        // A[m=lane&15][k=quad*8+j]
            a[t][ks] = *(const short8*)(arow + ks * 32);
        #pragma unroll
        for (int r = 0; r < 4; ++r)
            bo[t][r] = bias[ot * 16 + q * 4 + r];
    }

    floatx4 fl[12];

    // prologue: stage tile 0
    load_tile(tile0, fl);
    stage_tile(0, fl);
    __syncthreads();

    #pragma unroll
    for (int t = 0; t < T_TILES; ++t) {
        const int cur = t & 1;

        // issue next tile's loads FIRST — HBM latency hides under MFMA+stores
        if (t + 1 < T_TILES)
            load_tile(tile0 + t + 1, fl);

        // compute tile t from Xl[cur]
        floatx4 acc[3][4];
        #pragma unroll
        for (int tt = 0; tt < 3; ++tt)
            #pragma unroll
            for (int pt = 0; pt < 4; ++pt)
                acc[tt][pt] = (floatx4){0.f, 0.f, 0.f, 0.f};

        #pragma unroll
        for (int pt = 0; pt < 4; ++pt) {
            const unsigned short* brow =
                &Xl[cur][(pt * 16 + n) * LDS_STRIDE + q * 8];
            short8 bfr[6];
            #pragma unroll
            for (int ks = 0; ks < 6; ++ks)    // B[k=quad*8+j][n=lane&15]
                bfr[ks] = *(const short8*)(brow + ks * 32);
            #pragma unroll
            for (int tt = 0; tt < 3; ++tt)
                #pragma unroll
                for (int ks = 0; ks < 6; ++ks)
                    acc[tt][pt] = __builtin_amdgcn_mfma_f32_16x16x32_bf16(
                        a[tt][ks], bfr[ks], acc[tt][pt], 0, 0, 0);
        }

        // store tile t: D row = q*4 + r, col = n
        {
            const int tile = tile0 + t;
            float* ob = out + (size_t)(tile >> 8) * (CDIM * HWPX)
                            + ((tile & 255) << 6);
            #pragma unroll
            for (int tt = 0; tt < 3; ++tt) {
                #pragma unroll
                for (int r = 0; r < 4; ++r) {
                    const int o = (w * 3 + tt) * 16 + q * 4 + r;
                    float* orow = ob + (size_t)o * HWPX + n;
                    #pragma unroll
                    for (int pt = 0; pt < 4; ++pt)
                        orow[pt * 16] = acc[tt][pt][r] + bo[tt][r];
                }
            }
        }

        // now consume the prefetch: vmcnt wait happens here, not at issue
        if (t + 1 < T_TILES)
            stage_tile(cur ^ 1, fl);

        __syncthreads();
    }
}

extern "C" void kernel_launch(void* const* d_in, const int* in_sizes, int n_in,
                              void* d_out, int out_size, void* d_ws, size_t ws_size,
                              hipStream_t stream) {
    const float* x      = (const float*)d_in[0];
    const float* w_qkv  = (const float*)d_in[1];
    const float* b_qkv  = (const float*)d_in[2];
    // d_in[3] = w_attn, d_in[4] = b_attn: mathematically unused (softmax sums to 1)
    const float* w_proj = (const float*)d_in[5];
    const float* b_proj = (const float*)d_in[6];
    float* out = (float*)d_out;

    unsigned short* Mb = (unsigned short*)d_ws;                       // 192*192 bf16
    float* bias = (float*)((char*)d_ws + CDIM * CDIM * sizeof(unsigned short));

    const int B = in_sizes[0] / (CDIM * HWPX);  // 8

    prep_kernel<<<CDIM, CDIM, 0, stream>>>(w_qkv, b_qkv, w_proj, b_proj, Mb, bias);
    fused_kernel<<<(B * 256) / T_TILES, 256, 0, stream>>>(x, Mb, bias, out);
}